// Round 1
// baseline (604.394 us; speedup 1.0000x reference)
//
#include <hip/hip_runtime.h>
#include <cstdint>
#include <math.h>

#define HW 224
#define NPIX (HW*HW)          // 50176
#define BATCH 32
#define KP 64
#define PS 16
#define NCLS 1000

// ---------------------------------------------------------------------------
// K1: Harris response, masked. One 16x16 output tile per block, 20x20 g-halo.
// dx/dy use zero-padded grayscale; gauss uses zero-padded dx^2 (i.e. dx==0
// outside the image, NOT dx computed from padded g).
// ---------------------------------------------------------------------------
__global__ __launch_bounds__(256) void k_harris(const float* __restrict__ x,
                                                float* __restrict__ R) {
    const int bx = blockIdx.x, by = blockIdx.y, b = blockIdx.z;
    __shared__ float G[20][21];
    __shared__ float DX[18][19];
    __shared__ float DY[18][19];
    const int tid = threadIdx.x;
    const float* xb = x + (size_t)b * 3 * NPIX;

    for (int l = tid; l < 400; l += 256) {
        int p = l / 20, q = l % 20;
        int gy = by * 16 + p - 2, gx = bx * 16 + q - 2;
        float v = 0.f;
        if (gy >= 0 && gy < HW && gx >= 0 && gx < HW) {
            int o = gy * HW + gx;
            v = (xb[o] + xb[NPIX + o] + xb[2 * NPIX + o]) / 3.0f;
        }
        G[p][q] = v;
    }
    __syncthreads();

    for (int l = tid; l < 324; l += 256) {
        int a = l / 18, c = l % 18;
        int gy = by * 16 + a - 1, gx = bx * 16 + c - 1;
        float dxv = 0.f, dyv = 0.f;
        if (gy >= 0 && gy < HW && gx >= 0 && gx < HW) {
            dxv = (G[a][c + 2] - G[a][c]) + (G[a + 1][c + 2] - G[a + 1][c]) +
                  (G[a + 2][c + 2] - G[a + 2][c]);
            dyv = (G[a + 2][c] + G[a + 2][c + 1] + G[a + 2][c + 2]) -
                  (G[a][c] + G[a][c + 1] + G[a][c + 2]);
        }
        DX[a][c] = dxv;
        DY[a][c] = dyv;
    }
    __syncthreads();

    const int ty = tid / 16, tx = tid % 16;
    const int gy = by * 16 + ty, gx = bx * 16 + tx;
    float outv = 0.f;
    if (gy >= PS && gy < HW - PS && gx >= PS && gx < HW - PS) {
        const float gw[3][3] = {{1.f/16.f, 2.f/16.f, 1.f/16.f},
                                {2.f/16.f, 4.f/16.f, 2.f/16.f},
                                {1.f/16.f, 2.f/16.f, 1.f/16.f}};
        float sxx = 0.f, syy = 0.f, sxy = 0.f;
        #pragma unroll
        for (int u = 0; u < 3; u++)
            #pragma unroll
            for (int v = 0; v < 3; v++) {
                float dv = DX[ty + u][tx + v];
                float ev = DY[ty + u][tx + v];
                float w = gw[u][v];
                sxx += w * dv * dv;
                syy += w * ev * ev;
                sxy += w * dv * ev;
            }
        float tr = sxx + syy;
        outv = sxx * syy - sxy * sxy - 0.04f * tr * tr;
    }
    R[(size_t)b * NPIX + gy * HW + gx] = outv;
}

// ---------------------------------------------------------------------------
// K2: per-image top-64 (descending value, lower index wins ties -- matches
// jax.lax.top_k). One 1024-thread block per image; each thread caches its 49
// strided values in registers; 64 rounds of shuffle+LDS argmax with a
// per-thread taken-bitmask rescan by the owning thread.
// ---------------------------------------------------------------------------
__global__ __launch_bounds__(1024) void k_topk(const float* __restrict__ R,
                                               int* __restrict__ kp) {
    const int b = blockIdx.x;
    const int t = threadIdx.x;
    const float* Rb = R + (size_t)b * NPIX;

    float cv[49];
    #pragma unroll
    for (int e = 0; e < 49; e++) cv[e] = Rb[t + e * 1024];

    unsigned long long taken = 0ull;
    float lv = -INFINITY;
    int li = 0x7fffffff;
    #pragma unroll
    for (int e = 0; e < 49; e++) {
        float v = cv[e];
        if (v > lv) { lv = v; li = t + e * 1024; }  // ascending idx: > keeps earliest tie
    }

    __shared__ float wv[16];
    __shared__ int wi[16];
    __shared__ int ssel;

    for (int r = 0; r < 64; r++) {
        float rv = lv;
        int ri = li;
        #pragma unroll
        for (int off = 1; off < 64; off <<= 1) {
            float ov = __shfl_xor(rv, off, 64);
            int oi = __shfl_xor(ri, off, 64);
            if (ov > rv || (ov == rv && oi < ri)) { rv = ov; ri = oi; }
        }
        if ((t & 63) == 0) { wv[t >> 6] = rv; wi[t >> 6] = ri; }
        __syncthreads();
        if (t == 0) {
            float bv = wv[0];
            int bi = wi[0];
            for (int w = 1; w < 16; w++) {
                if (wv[w] > bv || (wv[w] == bv && wi[w] < bi)) { bv = wv[w]; bi = wi[w]; }
            }
            kp[b * KP + r] = bi;
            ssel = bi;
        }
        __syncthreads();
        const int sel = ssel;
        if ((sel & 1023) == t) {
            taken |= 1ull << (sel >> 10);
            lv = -INFINITY;
            li = 0x7fffffff;
            #pragma unroll
            for (int e = 0; e < 49; e++) {
                if (!(taken & (1ull << e))) {
                    float v = cv[e];
                    int idx = t + e * 1024;
                    if (v > lv || (v == lv && idx < li)) { lv = v; li = idx; }
                }
            }
        }
        __syncthreads();
    }
}

// ---------------------------------------------------------------------------
// K3: bilinear patch extraction (replicating the reference's swapped
// broadcast: gx driven by row/y01, gy by col/x01) + 3x3 conv + bias + relu.
// One block per (image, keypoint). Output h[m][co*256 + i*16 + j].
// ---------------------------------------------------------------------------
__device__ __forceinline__ float gat4(const float* img, float xf, float yf) {
    bool valid = (xf >= 0.f) && (xf < 224.f) && (yf >= 0.f) && (yf < 224.f);
    if (!valid) return 0.f;
    int xi = (int)fminf(fmaxf(xf, 0.f), 223.f);
    int yi = (int)fminf(fmaxf(yf, 0.f), 223.f);
    return img[yi * HW + xi];
}

__global__ __launch_bounds__(256) void k_patch_conv(
    const float* __restrict__ x, const int* __restrict__ kp,
    const float* __restrict__ conv_w, const float* __restrict__ conv_b,
    float* __restrict__ h) {
    const int s = blockIdx.x;   // keypoint slot
    const int b = blockIdx.y;   // image
    const int tid = threadIdx.x;

    __shared__ float P[3][16][16];
    __shared__ float CW[216];
    __shared__ float CB[8];
    for (int l = tid; l < 216; l += 256) CW[l] = conv_w[l];
    if (tid < 8) CB[tid] = conv_b[tid];

    const int idx = kp[b * KP + s];
    const int row = idx / HW, col = idx % HW;
    float cy = ((float)row / 224.0f - 0.5f) * 2.0f;
    float cx = ((float)col / 224.0f - 0.5f) * 2.0f;
    cy = fminf(fmaxf(cy, -1.0f), 1.0f);
    cx = fminf(fmaxf(cx, -1.0f), 1.0f);
    const float y01 = (cy + 1.0f) * 0.5f;
    const float x01 = (cx + 1.0f) * 0.5f;
    const float rr = 16.0f / 224.0f;
    const float step = (2.0f * rr) / 15.0f;
    const float* xb = x + (size_t)b * 3 * NPIX;

    for (int e = tid; e < 768; e += 256) {
        int c = e >> 8, rem = e & 255, i = rem >> 4, j = rem & 15;
        float pj = (j == 15) ? rr : (-rr + (float)j * step);
        float pi = (i == 15) ? rr : (-rr + (float)i * step);
        // faithful bug: x-coordinate uses y01 (row), y-coordinate uses x01 (col)
        float gxn = (pj + y01) * 2.0f - 1.0f;
        float gyn = (pi + x01) * 2.0f - 1.0f;
        float gx = (gxn + 1.0f) * 0.5f * 223.0f;
        float gy = (gyn + 1.0f) * 0.5f * 223.0f;
        float x0 = floorf(gx), y0 = floorf(gy);
        float x1 = x0 + 1.0f, y1 = y0 + 1.0f;
        float wx1 = gx - x0, wy1 = gy - y0;
        float wx0 = 1.0f - wx1, wy0 = 1.0f - wy1;
        const float* img = xb + (size_t)c * NPIX;
        float acc = gat4(img, x0, y0) * (wx0 * wy0)
                  + gat4(img, x1, y0) * (wx1 * wy0)
                  + gat4(img, x0, y1) * (wx0 * wy1)
                  + gat4(img, x1, y1) * (wx1 * wy1);
        P[c][i][j] = acc;
    }
    __syncthreads();

    const int i = tid >> 4, j = tid & 15;
    const size_t mbase = ((size_t)(b * KP + s)) * 2048;
    #pragma unroll
    for (int co = 0; co < 8; co++) {
        float acc = CB[co];
        #pragma unroll
        for (int ci = 0; ci < 3; ci++)
            #pragma unroll
            for (int di = 0; di < 3; di++)
                #pragma unroll
                for (int dj = 0; dj < 3; dj++) {
                    int yy = i + di - 1, xx = j + dj - 1;
                    if (yy >= 0 && yy < 16 && xx >= 0 && xx < 16)
                        acc += P[ci][yy][xx] * CW[co * 27 + ci * 9 + di * 3 + dj];
                }
        h[mbase + co * 256 + tid] = fmaxf(acc, 0.0f);
    }
}

// ---------------------------------------------------------------------------
// K4: fc1 GEMM  out[m][o] = relu(sum_f h[m][f]*fc1_w[o][f] + b[o]),
// M=2048, N=64, K=2048. 256 blocks x 8 rows; thread = (o, 2 m's).
// Writes featT[(s*64+o)*32 + b] (transposed for fc2 coalescing).
// ---------------------------------------------------------------------------
__global__ __launch_bounds__(256) void k_fc1(
    const float* __restrict__ h, const float* __restrict__ fc1_w,
    const float* __restrict__ fc1_b, float* __restrict__ featT) {
    const int blk = blockIdx.x;
    const int tid = threadIdx.x;
    const int M0 = blk * 8;
    __shared__ float A[8 * 64];     // [m][kc]
    __shared__ float W[64 * 68];    // [o][kc], row stride 68
    const int o = tid & 63, mg = tid >> 6;
    float acc0 = 0.f, acc1 = 0.f;

    for (int k0 = 0; k0 < 2048; k0 += 64) {
        __syncthreads();
        if (tid < 128) {
            int rw = tid >> 4, c4 = (tid & 15) << 2;
            *(float4*)&A[rw * 64 + c4] =
                *(const float4*)&h[(size_t)(M0 + rw) * 2048 + k0 + c4];
        }
        #pragma unroll
        for (int r = 0; r < 4; r++) {
            int l = tid + r * 256;
            int ow = l >> 4, c4 = (l & 15) << 2;
            *(float4*)&W[ow * 68 + c4] =
                *(const float4*)&fc1_w[(size_t)ow * 2048 + k0 + c4];
        }
        __syncthreads();
        #pragma unroll
        for (int kc = 0; kc < 64; kc += 4) {
            float4 wvv = *(float4*)&W[o * 68 + kc];
            float4 a0 = *(float4*)&A[mg * 64 + kc];
            float4 a1 = *(float4*)&A[(mg + 4) * 64 + kc];
            acc0 += wvv.x * a0.x + wvv.y * a0.y + wvv.z * a0.z + wvv.w * a0.w;
            acc1 += wvv.x * a1.x + wvv.y * a1.y + wvv.z * a1.z + wvv.w * a1.w;
        }
    }
    const float bo = fc1_b[o];
    float v0 = fmaxf(acc0 + bo, 0.f);
    float v1 = fmaxf(acc1 + bo, 0.f);
    int m0 = M0 + mg, m1 = M0 + mg + 4;
    featT[(size_t)((m0 & 63) * 64 + o) * 32 + (m0 >> 6)] = v0;
    featT[(size_t)((m1 & 63) * 64 + o) * 32 + (m1 >> 6)] = v1;
}

// ---------------------------------------------------------------------------
// K5: fc2  out[b][c] = sum_f featT[f][b]*fc2_w[c][f] + b2[c].
// 125 blocks x 8 classes x 32 images; feature chunks staged in LDS with
// pad-36 (bank = (4f+b)%32, conflict-free). Each fc2_w row read exactly once.
// ---------------------------------------------------------------------------
__global__ __launch_bounds__(256) void k_fc2(
    const float* __restrict__ featT, const float* __restrict__ fc2_w,
    const float* __restrict__ fc2_b, float* __restrict__ out) {
    const int blk = blockIdx.x;
    const int tid = threadIdx.x;
    __shared__ float F[128 * 36];
    const int cl = tid >> 5, b = tid & 31;
    const int c = blk * 8 + cl;
    float acc = 0.f;

    for (int k0 = 0; k0 < 4096; k0 += 128) {
        __syncthreads();
        #pragma unroll
        for (int r = 0; r < 4; r++) {
            int l = tid + r * 256;
            int f = l >> 3, b4 = (l & 7) << 2;
            *(float4*)&F[f * 36 + b4] =
                *(const float4*)&featT[(size_t)(k0 + f) * 32 + b4];
        }
        __syncthreads();
        const float* wrow = fc2_w + (size_t)c * 4096 + k0;
        #pragma unroll 8
        for (int f = 0; f < 128; f += 4) {
            float4 wvv = *(const float4*)&wrow[f];
            acc += F[f * 36 + b] * wvv.x + F[(f + 1) * 36 + b] * wvv.y +
                   F[(f + 2) * 36 + b] * wvv.z + F[(f + 3) * 36 + b] * wvv.w;
        }
    }
    out[b * NCLS + c] = acc + fc2_b[c];
}

// ---------------------------------------------------------------------------
extern "C" void kernel_launch(void* const* d_in, const int* in_sizes, int n_in,
                              void* d_out, int out_size, void* d_ws, size_t ws_size,
                              hipStream_t stream) {
    const float* x      = (const float*)d_in[0];
    const float* conv_w = (const float*)d_in[1];
    const float* conv_b = (const float*)d_in[2];
    const float* fc1_w  = (const float*)d_in[3];
    const float* fc1_b  = (const float*)d_in[4];
    const float* fc2_w  = (const float*)d_in[5];
    const float* fc2_b  = (const float*)d_in[6];
    float* out = (float*)d_out;

    // ws layout
    float* R     = (float*)d_ws;                       // 32*50176 floats
    int*   kp    = (int*)(R + (size_t)BATCH * NPIX);   // 32*64 ints
    float* h     = (float*)(kp + BATCH * KP);          // 2048*2048 floats
    float* featT = h + (size_t)2048 * 2048;            // 4096*32 floats

    k_harris<<<dim3(14, 14, 32), 256, 0, stream>>>(x, R);
    k_topk<<<32, 1024, 0, stream>>>(R, kp);
    k_patch_conv<<<dim3(KP, BATCH), 256, 0, stream>>>(x, kp, conv_w, conv_b, h);
    k_fc1<<<256, 256, 0, stream>>>(h, fc1_w, fc1_b, featT);
    k_fc2<<<125, 256, 0, stream>>>(featT, fc2_w, fc2_b, out);
}

// Round 2
// 373.980 us; speedup vs baseline: 1.6161x; 1.6161x over previous
//
#include <hip/hip_runtime.h>
#include <cstdint>
#include <math.h>

#define HW 224
#define NPIX (HW*HW)          // 50176 = 784*64
#define BATCH 32
#define KP 64
#define PS 16
#define NCLS 1000
#define TK_WAVES 16           // waves per image in phase 1
#define TK_CHUNK (NPIX / TK_WAVES)   // 3136 = 49*64
#define TK_ITERS (TK_CHUNK / 64)     // 49

// ---------------------------------------------------------------------------
// K1: Harris response, masked. One 16x16 output tile per block, 20x20 g-halo.
// ---------------------------------------------------------------------------
__global__ __launch_bounds__(256) void k_harris(const float* __restrict__ x,
                                                float* __restrict__ R) {
    const int bx = blockIdx.x, by = blockIdx.y, b = blockIdx.z;
    __shared__ float G[20][21];
    __shared__ float DX[18][19];
    __shared__ float DY[18][19];
    const int tid = threadIdx.x;
    const float* xb = x + (size_t)b * 3 * NPIX;

    for (int l = tid; l < 400; l += 256) {
        int p = l / 20, q = l % 20;
        int gy = by * 16 + p - 2, gx = bx * 16 + q - 2;
        float v = 0.f;
        if (gy >= 0 && gy < HW && gx >= 0 && gx < HW) {
            int o = gy * HW + gx;
            v = (xb[o] + xb[NPIX + o] + xb[2 * NPIX + o]) / 3.0f;
        }
        G[p][q] = v;
    }
    __syncthreads();

    for (int l = tid; l < 324; l += 256) {
        int a = l / 18, c = l % 18;
        int gy = by * 16 + a - 1, gx = bx * 16 + c - 1;
        float dxv = 0.f, dyv = 0.f;
        if (gy >= 0 && gy < HW && gx >= 0 && gx < HW) {
            dxv = (G[a][c + 2] - G[a][c]) + (G[a + 1][c + 2] - G[a + 1][c]) +
                  (G[a + 2][c + 2] - G[a + 2][c]);
            dyv = (G[a + 2][c] + G[a + 2][c + 1] + G[a + 2][c + 2]) -
                  (G[a][c] + G[a][c + 1] + G[a][c + 2]);
        }
        DX[a][c] = dxv;
        DY[a][c] = dyv;
    }
    __syncthreads();

    const int ty = tid / 16, tx = tid % 16;
    const int gy = by * 16 + ty, gx = bx * 16 + tx;
    float outv = 0.f;
    if (gy >= PS && gy < HW - PS && gx >= PS && gx < HW - PS) {
        const float gw[3][3] = {{1.f/16.f, 2.f/16.f, 1.f/16.f},
                                {2.f/16.f, 4.f/16.f, 2.f/16.f},
                                {1.f/16.f, 2.f/16.f, 1.f/16.f}};
        float sxx = 0.f, syy = 0.f, sxy = 0.f;
        #pragma unroll
        for (int u = 0; u < 3; u++)
            #pragma unroll
            for (int v = 0; v < 3; v++) {
                float dv = DX[ty + u][tx + v];
                float ev = DY[ty + u][tx + v];
                float w = gw[u][v];
                sxx += w * dv * dv;
                syy += w * ev * ev;
                sxy += w * dv * ev;
            }
        float tr = sxx + syy;
        outv = sxx * syy - sxy * sxy - 0.04f * tr * tr;
    }
    R[(size_t)b * NPIX + gy * HW + gx] = outv;
}

// ---------------------------------------------------------------------------
// Top-64: in-wave bitonic selection on packed 64-bit keys.
// key = monotone(value) << 32 | ~index  -> order == (value desc, index asc).
// ---------------------------------------------------------------------------
__device__ __forceinline__ uint64_t tk_pack(float v, int idx) {
    uint32_t u = __float_as_uint(v);
    u = (u & 0x80000000u) ? ~u : (u | 0x80000000u);
    return ((uint64_t)u << 32) | (uint32_t)(~idx);
}

// full in-wave bitonic sort, ascending across lanes (21 exchange steps)
__device__ __forceinline__ uint64_t tk_sort_asc(uint64_t k, int lane) {
    #pragma unroll
    for (int size = 2; size <= 64; size <<= 1) {
        #pragma unroll
        for (int stride = size >> 1; stride >= 1; stride >>= 1) {
            uint64_t o = __shfl_xor(k, stride, 64);
            bool up = ((lane & size) == 0);
            bool keepmax = (((lane & stride) != 0) == up);
            k = keepmax ? (k > o ? k : o) : (k < o ? k : o);
        }
    }
    return k;
}

// clean a bitonic sequence into descending order (6 exchange steps)
__device__ __forceinline__ uint64_t tk_clean_desc(uint64_t k, int lane) {
    #pragma unroll
    for (int stride = 32; stride >= 1; stride >>= 1) {
        uint64_t o = __shfl_xor(k, stride, 64);
        bool keepmax = ((lane & stride) == 0);
        k = keepmax ? (k > o ? k : o) : (k < o ? k : o);
    }
    return k;
}

// Phase 1: grid (4, 32) x 256 threads = 16 waves/image, chunk = 3136 elems.
// Each wave keeps a running descending top-64; threshold-ballot skips batches
// that cannot contribute (exact: later batches have strictly higher indices,
// so equal packed keys never displace).
__global__ __launch_bounds__(256) void k_topk_part(const float* __restrict__ R,
                                                   uint64_t* __restrict__ cand) {
    const int img = blockIdx.y;
    const int wave = blockIdx.x * 4 + (threadIdx.x >> 6);
    const int lane = threadIdx.x & 63;
    const float* base = R + (size_t)img * NPIX + wave * TK_CHUNK;
    const int idx_base = wave * TK_CHUNK + lane;

    uint64_t T = 0;  // all-minimal, trivially "descending"
    #pragma unroll 1
    for (int it = 0; it < TK_ITERS; it++) {
        float v = base[it * 64 + lane];
        uint64_t ck = tk_pack(v, idx_base + it * 64);
        uint64_t thr = __shfl(T, 63, 64);          // current 64th-best key
        if (__ballot(ck > thr)) {
            uint64_t s = tk_sort_asc(ck, lane);
            uint64_t m = (T > s) ? T : s;          // top-64 of union (bitonic)
            T = tk_clean_desc(m, lane);
        }
    }
    cand[((size_t)img * TK_WAVES + wave) * 64 + lane] = T;
}

// Phase 2: one wave per image; 15 sorted-run merges, then unpack indices.
__global__ __launch_bounds__(64) void k_topk_merge(const uint64_t* __restrict__ cand,
                                                   int* __restrict__ kp) {
    const int img = blockIdx.x;
    const int lane = threadIdx.x;
    const uint64_t* cb = cand + (size_t)img * TK_WAVES * 64;
    uint64_t T = cb[lane];                          // run 0, descending
    #pragma unroll
    for (int w = 1; w < TK_WAVES; w++) {
        uint64_t C = cb[w * 64 + (63 - lane)];      // reversed -> ascending
        uint64_t m = (T > C) ? T : C;
        T = tk_clean_desc(m, lane);
    }
    kp[img * KP + lane] = (int)(~(uint32_t)T);      // rank 'lane' keypoint
}

// ---------------------------------------------------------------------------
// K3: bilinear patch extraction (faithful swapped broadcast) + conv + relu.
// ---------------------------------------------------------------------------
__device__ __forceinline__ float gat4(const float* img, float xf, float yf) {
    bool valid = (xf >= 0.f) && (xf < 224.f) && (yf >= 0.f) && (yf < 224.f);
    if (!valid) return 0.f;
    int xi = (int)fminf(fmaxf(xf, 0.f), 223.f);
    int yi = (int)fminf(fmaxf(yf, 0.f), 223.f);
    return img[yi * HW + xi];
}

__global__ __launch_bounds__(256) void k_patch_conv(
    const float* __restrict__ x, const int* __restrict__ kp,
    const float* __restrict__ conv_w, const float* __restrict__ conv_b,
    float* __restrict__ h) {
    const int s = blockIdx.x;   // keypoint slot
    const int b = blockIdx.y;   // image
    const int tid = threadIdx.x;

    __shared__ float P[3][16][16];
    __shared__ float CW[216];
    __shared__ float CB[8];
    for (int l = tid; l < 216; l += 256) CW[l] = conv_w[l];
    if (tid < 8) CB[tid] = conv_b[tid];

    const int idx = kp[b * KP + s];
    const int row = idx / HW, col = idx % HW;
    float cy = ((float)row / 224.0f - 0.5f) * 2.0f;
    float cx = ((float)col / 224.0f - 0.5f) * 2.0f;
    cy = fminf(fmaxf(cy, -1.0f), 1.0f);
    cx = fminf(fmaxf(cx, -1.0f), 1.0f);
    const float y01 = (cy + 1.0f) * 0.5f;
    const float x01 = (cx + 1.0f) * 0.5f;
    const float rr = 16.0f / 224.0f;
    const float step = (2.0f * rr) / 15.0f;
    const float* xb = x + (size_t)b * 3 * NPIX;

    for (int e = tid; e < 768; e += 256) {
        int c = e >> 8, rem = e & 255, i = rem >> 4, j = rem & 15;
        float pj = (j == 15) ? rr : (-rr + (float)j * step);
        float pi = (i == 15) ? rr : (-rr + (float)i * step);
        // faithful bug: x-coordinate uses y01 (row), y-coordinate uses x01 (col)
        float gxn = (pj + y01) * 2.0f - 1.0f;
        float gyn = (pi + x01) * 2.0f - 1.0f;
        float gx = (gxn + 1.0f) * 0.5f * 223.0f;
        float gy = (gyn + 1.0f) * 0.5f * 223.0f;
        float x0 = floorf(gx), y0 = floorf(gy);
        float x1 = x0 + 1.0f, y1 = y0 + 1.0f;
        float wx1 = gx - x0, wy1 = gy - y0;
        float wx0 = 1.0f - wx1, wy0 = 1.0f - wy1;
        const float* img = xb + (size_t)c * NPIX;
        float acc = gat4(img, x0, y0) * (wx0 * wy0)
                  + gat4(img, x1, y0) * (wx1 * wy0)
                  + gat4(img, x0, y1) * (wx0 * wy1)
                  + gat4(img, x1, y1) * (wx1 * wy1);
        P[c][i][j] = acc;
    }
    __syncthreads();

    const int i = tid >> 4, j = tid & 15;
    const size_t mbase = ((size_t)(b * KP + s)) * 2048;
    #pragma unroll
    for (int co = 0; co < 8; co++) {
        float acc = CB[co];
        #pragma unroll
        for (int ci = 0; ci < 3; ci++)
            #pragma unroll
            for (int di = 0; di < 3; di++)
                #pragma unroll
                for (int dj = 0; dj < 3; dj++) {
                    int yy = i + di - 1, xx = j + dj - 1;
                    if (yy >= 0 && yy < 16 && xx >= 0 && xx < 16)
                        acc += P[ci][yy][xx] * CW[co * 27 + ci * 9 + di * 3 + dj];
                }
        h[mbase + co * 256 + tid] = fmaxf(acc, 0.0f);
    }
}

// ---------------------------------------------------------------------------
// K4: fc1 GEMM  M=2048, N=64, K=2048 -> featT [(s*64+o)*32 + b]
// ---------------------------------------------------------------------------
__global__ __launch_bounds__(256) void k_fc1(
    const float* __restrict__ h, const float* __restrict__ fc1_w,
    const float* __restrict__ fc1_b, float* __restrict__ featT) {
    const int blk = blockIdx.x;
    const int tid = threadIdx.x;
    const int M0 = blk * 8;
    __shared__ float A[8 * 64];
    __shared__ float W[64 * 68];
    const int o = tid & 63, mg = tid >> 6;
    float acc0 = 0.f, acc1 = 0.f;

    for (int k0 = 0; k0 < 2048; k0 += 64) {
        __syncthreads();
        if (tid < 128) {
            int rw = tid >> 4, c4 = (tid & 15) << 2;
            *(float4*)&A[rw * 64 + c4] =
                *(const float4*)&h[(size_t)(M0 + rw) * 2048 + k0 + c4];
        }
        #pragma unroll
        for (int r = 0; r < 4; r++) {
            int l = tid + r * 256;
            int ow = l >> 4, c4 = (l & 15) << 2;
            *(float4*)&W[ow * 68 + c4] =
                *(const float4*)&fc1_w[(size_t)ow * 2048 + k0 + c4];
        }
        __syncthreads();
        #pragma unroll
        for (int kc = 0; kc < 64; kc += 4) {
            float4 wvv = *(float4*)&W[o * 68 + kc];
            float4 a0 = *(float4*)&A[mg * 64 + kc];
            float4 a1 = *(float4*)&A[(mg + 4) * 64 + kc];
            acc0 += wvv.x * a0.x + wvv.y * a0.y + wvv.z * a0.z + wvv.w * a0.w;
            acc1 += wvv.x * a1.x + wvv.y * a1.y + wvv.z * a1.z + wvv.w * a1.w;
        }
    }
    const float bo = fc1_b[o];
    float v0 = fmaxf(acc0 + bo, 0.f);
    float v1 = fmaxf(acc1 + bo, 0.f);
    int m0 = M0 + mg, m1 = M0 + mg + 4;
    featT[(size_t)((m0 & 63) * 64 + o) * 32 + (m0 >> 6)] = v0;
    featT[(size_t)((m1 & 63) * 64 + o) * 32 + (m1 >> 6)] = v1;
}

// ---------------------------------------------------------------------------
// K5: fc2  out[b][c] = sum_f featT[f][b]*fc2_w[c][f] + b2[c]
// ---------------------------------------------------------------------------
__global__ __launch_bounds__(256) void k_fc2(
    const float* __restrict__ featT, const float* __restrict__ fc2_w,
    const float* __restrict__ fc2_b, float* __restrict__ out) {
    const int blk = blockIdx.x;
    const int tid = threadIdx.x;
    __shared__ float F[128 * 36];
    const int cl = tid >> 5, b = tid & 31;
    const int c = blk * 8 + cl;
    float acc = 0.f;

    for (int k0 = 0; k0 < 4096; k0 += 128) {
        __syncthreads();
        #pragma unroll
        for (int r = 0; r < 4; r++) {
            int l = tid + r * 256;
            int f = l >> 3, b4 = (l & 7) << 2;
            *(float4*)&F[f * 36 + b4] =
                *(const float4*)&featT[(size_t)(k0 + f) * 32 + b4];
        }
        __syncthreads();
        const float* wrow = fc2_w + (size_t)c * 4096 + k0;
        #pragma unroll 8
        for (int f = 0; f < 128; f += 4) {
            float4 wvv = *(const float4*)&wrow[f];
            acc += F[f * 36 + b] * wvv.x + F[(f + 1) * 36 + b] * wvv.y +
                   F[(f + 2) * 36 + b] * wvv.z + F[(f + 3) * 36 + b] * wvv.w;
        }
    }
    out[b * NCLS + c] = acc + fc2_b[c];
}

// ---------------------------------------------------------------------------
extern "C" void kernel_launch(void* const* d_in, const int* in_sizes, int n_in,
                              void* d_out, int out_size, void* d_ws, size_t ws_size,
                              hipStream_t stream) {
    const float* x      = (const float*)d_in[0];
    const float* conv_w = (const float*)d_in[1];
    const float* conv_b = (const float*)d_in[2];
    const float* fc1_w  = (const float*)d_in[3];
    const float* fc1_b  = (const float*)d_in[4];
    const float* fc2_w  = (const float*)d_in[5];
    const float* fc2_b  = (const float*)d_in[6];
    float* out = (float*)d_out;

    // ws layout (all 8B-aligned)
    float*    R     = (float*)d_ws;                                   // 32*50176 f
    uint64_t* cand  = (uint64_t*)(R + (size_t)BATCH * NPIX);          // 32*16*64 u64
    int*      kp    = (int*)(cand + (size_t)BATCH * TK_WAVES * 64);   // 32*64 int
    float*    h     = (float*)(kp + BATCH * KP);                      // 2048*2048 f
    float*    featT = h + (size_t)2048 * 2048;                        // 4096*32 f

    k_harris<<<dim3(14, 14, 32), 256, 0, stream>>>(x, R);
    k_topk_part<<<dim3(4, 32), 256, 0, stream>>>(R, cand);
    k_topk_merge<<<32, 64, 0, stream>>>(cand, kp);
    k_patch_conv<<<dim3(KP, BATCH), 256, 0, stream>>>(x, kp, conv_w, conv_b, h);
    k_fc1<<<256, 256, 0, stream>>>(h, fc1_w, fc1_b, featT);
    k_fc2<<<125, 256, 0, stream>>>(featT, fc2_w, fc2_b, out);
}

// Round 3
// 271.956 us; speedup vs baseline: 2.2224x; 1.3752x over previous
//
#include <hip/hip_runtime.h>
#include <cstdint>
#include <math.h>

#define HW 224
#define NPIX (HW*HW)          // 50176 = 784*64
#define BATCH 32
#define KP 64
#define PS 16
#define NCLS 1000
#define TK_WAVES 16           // waves per image in phase 1
#define TK_CHUNK (NPIX / TK_WAVES)   // 3136 = 49*64
#define TK_ITERS (TK_CHUNK / 64)     // 49

// ---------------------------------------------------------------------------
// K1: Harris response, masked. One 16x16 output tile per block, 20x20 g-halo.
// ---------------------------------------------------------------------------
__global__ __launch_bounds__(256) void k_harris(const float* __restrict__ x,
                                                float* __restrict__ R) {
    const int bx = blockIdx.x, by = blockIdx.y, b = blockIdx.z;
    __shared__ float G[20][21];
    __shared__ float DX[18][19];
    __shared__ float DY[18][19];
    const int tid = threadIdx.x;
    const float* xb = x + (size_t)b * 3 * NPIX;

    for (int l = tid; l < 400; l += 256) {
        int p = l / 20, q = l % 20;
        int gy = by * 16 + p - 2, gx = bx * 16 + q - 2;
        float v = 0.f;
        if (gy >= 0 && gy < HW && gx >= 0 && gx < HW) {
            int o = gy * HW + gx;
            v = (xb[o] + xb[NPIX + o] + xb[2 * NPIX + o]) / 3.0f;
        }
        G[p][q] = v;
    }
    __syncthreads();

    for (int l = tid; l < 324; l += 256) {
        int a = l / 18, c = l % 18;
        int gy = by * 16 + a - 1, gx = bx * 16 + c - 1;
        float dxv = 0.f, dyv = 0.f;
        if (gy >= 0 && gy < HW && gx >= 0 && gx < HW) {
            dxv = (G[a][c + 2] - G[a][c]) + (G[a + 1][c + 2] - G[a + 1][c]) +
                  (G[a + 2][c + 2] - G[a + 2][c]);
            dyv = (G[a + 2][c] + G[a + 2][c + 1] + G[a + 2][c + 2]) -
                  (G[a][c] + G[a][c + 1] + G[a][c + 2]);
        }
        DX[a][c] = dxv;
        DY[a][c] = dyv;
    }
    __syncthreads();

    const int ty = tid / 16, tx = tid % 16;
    const int gy = by * 16 + ty, gx = bx * 16 + tx;
    float outv = 0.f;
    if (gy >= PS && gy < HW - PS && gx >= PS && gx < HW - PS) {
        const float gw[3][3] = {{1.f/16.f, 2.f/16.f, 1.f/16.f},
                                {2.f/16.f, 4.f/16.f, 2.f/16.f},
                                {1.f/16.f, 2.f/16.f, 1.f/16.f}};
        float sxx = 0.f, syy = 0.f, sxy = 0.f;
        #pragma unroll
        for (int u = 0; u < 3; u++)
            #pragma unroll
            for (int v = 0; v < 3; v++) {
                float dv = DX[ty + u][tx + v];
                float ev = DY[ty + u][tx + v];
                float w = gw[u][v];
                sxx += w * dv * dv;
                syy += w * ev * ev;
                sxy += w * dv * ev;
            }
        float tr = sxx + syy;
        outv = sxx * syy - sxy * sxy - 0.04f * tr * tr;
    }
    R[(size_t)b * NPIX + gy * HW + gx] = outv;
}

// ---------------------------------------------------------------------------
// Top-64: in-wave bitonic selection on packed 64-bit keys.
// key = monotone(value) << 32 | ~index  -> order == (value desc, index asc).
// ---------------------------------------------------------------------------
__device__ __forceinline__ uint64_t tk_pack(float v, int idx) {
    uint32_t u = __float_as_uint(v);
    u = (u & 0x80000000u) ? ~u : (u | 0x80000000u);
    return ((uint64_t)u << 32) | (uint32_t)(~idx);
}

__device__ __forceinline__ uint64_t tk_sort_asc(uint64_t k, int lane) {
    #pragma unroll
    for (int size = 2; size <= 64; size <<= 1) {
        #pragma unroll
        for (int stride = size >> 1; stride >= 1; stride >>= 1) {
            uint64_t o = __shfl_xor(k, stride, 64);
            bool up = ((lane & size) == 0);
            bool keepmax = (((lane & stride) != 0) == up);
            k = keepmax ? (k > o ? k : o) : (k < o ? k : o);
        }
    }
    return k;
}

__device__ __forceinline__ uint64_t tk_clean_desc(uint64_t k, int lane) {
    #pragma unroll
    for (int stride = 32; stride >= 1; stride >>= 1) {
        uint64_t o = __shfl_xor(k, stride, 64);
        bool keepmax = ((lane & stride) == 0);
        k = keepmax ? (k > o ? k : o) : (k < o ? k : o);
    }
    return k;
}

__global__ __launch_bounds__(256) void k_topk_part(const float* __restrict__ R,
                                                   uint64_t* __restrict__ cand) {
    const int img = blockIdx.y;
    const int wave = blockIdx.x * 4 + (threadIdx.x >> 6);
    const int lane = threadIdx.x & 63;
    const float* base = R + (size_t)img * NPIX + wave * TK_CHUNK;
    const int idx_base = wave * TK_CHUNK + lane;

    uint64_t T = 0;
    #pragma unroll 1
    for (int it = 0; it < TK_ITERS; it++) {
        float v = base[it * 64 + lane];
        uint64_t ck = tk_pack(v, idx_base + it * 64);
        uint64_t thr = __shfl(T, 63, 64);
        if (__ballot(ck > thr)) {
            uint64_t s = tk_sort_asc(ck, lane);
            uint64_t m = (T > s) ? T : s;
            T = tk_clean_desc(m, lane);
        }
    }
    cand[((size_t)img * TK_WAVES + wave) * 64 + lane] = T;
}

__global__ __launch_bounds__(64) void k_topk_merge(const uint64_t* __restrict__ cand,
                                                   int* __restrict__ kp) {
    const int img = blockIdx.x;
    const int lane = threadIdx.x;
    const uint64_t* cb = cand + (size_t)img * TK_WAVES * 64;
    uint64_t T = cb[lane];
    #pragma unroll
    for (int w = 1; w < TK_WAVES; w++) {
        uint64_t C = cb[w * 64 + (63 - lane)];
        uint64_t m = (T > C) ? T : C;
        T = tk_clean_desc(m, lane);
    }
    kp[img * KP + lane] = (int)(~(uint32_t)T);
}

// ---------------------------------------------------------------------------
// K3: bilinear patch extraction (faithful swapped broadcast) + conv + relu.
// ---------------------------------------------------------------------------
__device__ __forceinline__ float gat4(const float* img, float xf, float yf) {
    bool valid = (xf >= 0.f) && (xf < 224.f) && (yf >= 0.f) && (yf < 224.f);
    if (!valid) return 0.f;
    int xi = (int)fminf(fmaxf(xf, 0.f), 223.f);
    int yi = (int)fminf(fmaxf(yf, 0.f), 223.f);
    return img[yi * HW + xi];
}

__global__ __launch_bounds__(256) void k_patch_conv(
    const float* __restrict__ x, const int* __restrict__ kp,
    const float* __restrict__ conv_w, const float* __restrict__ conv_b,
    float* __restrict__ h) {
    const int s = blockIdx.x;   // keypoint slot
    const int b = blockIdx.y;   // image
    const int tid = threadIdx.x;

    __shared__ float P[3][16][16];
    __shared__ float CW[216];
    __shared__ float CB[8];
    for (int l = tid; l < 216; l += 256) CW[l] = conv_w[l];
    if (tid < 8) CB[tid] = conv_b[tid];

    const int idx = kp[b * KP + s];
    const int row = idx / HW, col = idx % HW;
    float cy = ((float)row / 224.0f - 0.5f) * 2.0f;
    float cx = ((float)col / 224.0f - 0.5f) * 2.0f;
    cy = fminf(fmaxf(cy, -1.0f), 1.0f);
    cx = fminf(fmaxf(cx, -1.0f), 1.0f);
    const float y01 = (cy + 1.0f) * 0.5f;
    const float x01 = (cx + 1.0f) * 0.5f;
    const float rr = 16.0f / 224.0f;
    const float step = (2.0f * rr) / 15.0f;
    const float* xb = x + (size_t)b * 3 * NPIX;

    for (int e = tid; e < 768; e += 256) {
        int c = e >> 8, rem = e & 255, i = rem >> 4, j = rem & 15;
        float pj = (j == 15) ? rr : (-rr + (float)j * step);
        float pi = (i == 15) ? rr : (-rr + (float)i * step);
        // faithful bug: x-coordinate uses y01 (row), y-coordinate uses x01 (col)
        float gxn = (pj + y01) * 2.0f - 1.0f;
        float gyn = (pi + x01) * 2.0f - 1.0f;
        float gx = (gxn + 1.0f) * 0.5f * 223.0f;
        float gy = (gyn + 1.0f) * 0.5f * 223.0f;
        float x0 = floorf(gx), y0 = floorf(gy);
        float x1 = x0 + 1.0f, y1 = y0 + 1.0f;
        float wx1 = gx - x0, wy1 = gy - y0;
        float wx0 = 1.0f - wx1, wy0 = 1.0f - wy1;
        const float* img = xb + (size_t)c * NPIX;
        float acc = gat4(img, x0, y0) * (wx0 * wy0)
                  + gat4(img, x1, y0) * (wx1 * wy0)
                  + gat4(img, x0, y1) * (wx0 * wy1)
                  + gat4(img, x1, y1) * (wx1 * wy1);
        P[c][i][j] = acc;
    }
    __syncthreads();

    const int i = tid >> 4, j = tid & 15;
    const size_t mbase = ((size_t)(b * KP + s)) * 2048;
    #pragma unroll
    for (int co = 0; co < 8; co++) {
        float acc = CB[co];
        #pragma unroll
        for (int ci = 0; ci < 3; ci++)
            #pragma unroll
            for (int di = 0; di < 3; di++)
                #pragma unroll
                for (int dj = 0; dj < 3; dj++) {
                    int yy = i + di - 1, xx = j + dj - 1;
                    if (yy >= 0 && yy < 16 && xx >= 0 && xx < 16)
                        acc += P[ci][yy][xx] * CW[co * 27 + ci * 9 + di * 3 + dj];
                }
        h[mbase + co * 256 + tid] = fmaxf(acc, 0.0f);
    }
}

// ---------------------------------------------------------------------------
// K4: fc1 GEMM  M=2048, N=64, K=2048 -> featT [(s*64+o)*32 + b]
// ---------------------------------------------------------------------------
__global__ __launch_bounds__(256) void k_fc1(
    const float* __restrict__ h, const float* __restrict__ fc1_w,
    const float* __restrict__ fc1_b, float* __restrict__ featT) {
    const int blk = blockIdx.x;
    const int tid = threadIdx.x;
    const int M0 = blk * 8;
    __shared__ float A[8 * 64];
    __shared__ float W[64 * 68];
    const int o = tid & 63, mg = tid >> 6;
    float acc0 = 0.f, acc1 = 0.f;

    for (int k0 = 0; k0 < 2048; k0 += 64) {
        __syncthreads();
        if (tid < 128) {
            int rw = tid >> 4, c4 = (tid & 15) << 2;
            *(float4*)&A[rw * 64 + c4] =
                *(const float4*)&h[(size_t)(M0 + rw) * 2048 + k0 + c4];
        }
        #pragma unroll
        for (int r = 0; r < 4; r++) {
            int l = tid + r * 256;
            int ow = l >> 4, c4 = (l & 15) << 2;
            *(float4*)&W[ow * 68 + c4] =
                *(const float4*)&fc1_w[(size_t)ow * 2048 + k0 + c4];
        }
        __syncthreads();
        #pragma unroll
        for (int kc = 0; kc < 64; kc += 4) {
            float4 wvv = *(float4*)&W[o * 68 + kc];
            float4 a0 = *(float4*)&A[mg * 64 + kc];
            float4 a1 = *(float4*)&A[(mg + 4) * 64 + kc];
            acc0 += wvv.x * a0.x + wvv.y * a0.y + wvv.z * a0.z + wvv.w * a0.w;
            acc1 += wvv.x * a1.x + wvv.y * a1.y + wvv.z * a1.z + wvv.w * a1.w;
        }
    }
    const float bo = fc1_b[o];
    float v0 = fmaxf(acc0 + bo, 0.f);
    float v1 = fmaxf(acc1 + bo, 0.f);
    int m0 = M0 + mg, m1 = M0 + mg + 4;
    featT[(size_t)((m0 & 63) * 64 + o) * 32 + (m0 >> 6)] = v0;
    featT[(size_t)((m1 & 63) * 64 + o) * 32 + (m1 >> 6)] = v1;
}

// ---------------------------------------------------------------------------
// K5a: init out[b][c] = fc2_b[c]  (d_out is poisoned before every launch)
// ---------------------------------------------------------------------------
__global__ __launch_bounds__(256) void k_bias(const float* __restrict__ fc2_b,
                                              float* __restrict__ out) {
    int id = blockIdx.x * 256 + threadIdx.x;
    if (id < BATCH * NCLS) out[id] = fc2_b[id % NCLS];
}

// ---------------------------------------------------------------------------
// K5b: fc2  out[b][c] += sum_k featT[k][b]*fc2_w[c][k], K split 8 ways.
// grid (125, 8): blockIdx.x -> 8 classes, blockIdx.y -> K slice of 512.
// featT chunk staged in LDS pad-36 (bank (4f+b)%32, conflict-free); w chunk
// staged coalesced, read back as broadcast. Per-thread: 8 class partials over
// 16 k's per chunk; LDS reduce over the 8 k-groups; one atomicAdd per (b,c).
// ---------------------------------------------------------------------------
__global__ __launch_bounds__(256) void k_fc2(
    const float* __restrict__ featT, const float* __restrict__ fc2_w,
    float* __restrict__ out) {
    const int c0 = blockIdx.x * 8;
    const int kbase = blockIdx.y * 512;
    const int tid = threadIdx.x;
    const int b = tid & 31, kg = tid >> 5;   // kg in [0,8)
    __shared__ float F[128 * 36];            // featT chunk [f][b], pad 36
    __shared__ float Wc[8 * 128];            // w chunk [cl][koff]
    __shared__ float Red[8 * 8 * 32];        // [kg][cl][b]

    float acc[8];
    #pragma unroll
    for (int cl = 0; cl < 8; cl++) acc[cl] = 0.f;

    #pragma unroll 1
    for (int ch = 0; ch < 4; ch++) {
        const int k0 = kbase + ch * 128;
        __syncthreads();
        #pragma unroll
        for (int r = 0; r < 4; r++) {
            int l = tid + r * 256;
            int f = l >> 3, b4 = (l & 7) << 2;
            *(float4*)&F[f * 36 + b4] =
                *(const float4*)&featT[(size_t)(k0 + f) * 32 + b4];
        }
        {
            int cl = tid >> 5, koff = (tid & 31) << 2;
            *(float4*)&Wc[cl * 128 + koff] =
                *(const float4*)&fc2_w[(size_t)(c0 + cl) * 4096 + k0 + koff];
        }
        __syncthreads();
        #pragma unroll
        for (int cl = 0; cl < 8; cl++) {
            #pragma unroll
            for (int i = 0; i < 16; i += 4) {
                float4 wv = *(float4*)&Wc[cl * 128 + kg * 16 + i];
                int f = kg * 16 + i;
                acc[cl] += wv.x * F[f * 36 + b] + wv.y * F[(f + 1) * 36 + b] +
                           wv.z * F[(f + 2) * 36 + b] + wv.w * F[(f + 3) * 36 + b];
            }
        }
    }
    __syncthreads();
    #pragma unroll
    for (int cl = 0; cl < 8; cl++) Red[(kg * 8 + cl) * 32 + b] = acc[cl];
    __syncthreads();
    const int cl2 = tid >> 5, b2 = tid & 31;
    float s = 0.f;
    #pragma unroll
    for (int g = 0; g < 8; g++) s += Red[(g * 8 + cl2) * 32 + b2];
    atomicAdd(&out[b2 * NCLS + c0 + cl2], s);
}

// ---------------------------------------------------------------------------
extern "C" void kernel_launch(void* const* d_in, const int* in_sizes, int n_in,
                              void* d_out, int out_size, void* d_ws, size_t ws_size,
                              hipStream_t stream) {
    const float* x      = (const float*)d_in[0];
    const float* conv_w = (const float*)d_in[1];
    const float* conv_b = (const float*)d_in[2];
    const float* fc1_w  = (const float*)d_in[3];
    const float* fc1_b  = (const float*)d_in[4];
    const float* fc2_w  = (const float*)d_in[5];
    const float* fc2_b  = (const float*)d_in[6];
    float* out = (float*)d_out;

    // ws layout (all 8B-aligned)
    float*    R     = (float*)d_ws;                                   // 32*50176 f
    uint64_t* cand  = (uint64_t*)(R + (size_t)BATCH * NPIX);          // 32*16*64 u64
    int*      kp    = (int*)(cand + (size_t)BATCH * TK_WAVES * 64);   // 32*64 int
    float*    h     = (float*)(kp + BATCH * KP);                      // 2048*2048 f
    float*    featT = h + (size_t)2048 * 2048;                        // 4096*32 f

    k_harris<<<dim3(14, 14, 32), 256, 0, stream>>>(x, R);
    k_topk_part<<<dim3(4, 32), 256, 0, stream>>>(R, cand);
    k_topk_merge<<<32, 64, 0, stream>>>(cand, kp);
    k_patch_conv<<<dim3(KP, BATCH), 256, 0, stream>>>(x, kp, conv_w, conv_b, h);
    k_fc1<<<256, 256, 0, stream>>>(h, fc1_w, fc1_b, featT);
    k_bias<<<(BATCH * NCLS + 255) / 256, 256, 0, stream>>>(fc2_b, out);
    k_fc2<<<dim3(125, 8), 256, 0, stream>>>(featT, fc2_w, out);
}

// Round 4
// 186.548 us; speedup vs baseline: 3.2399x; 1.4578x over previous
//
#include <hip/hip_runtime.h>
#include <cstdint>
#include <math.h>

#define HW 224
#define NPIX (HW*HW)          // 50176 = 784*64
#define BATCH 32
#define KP 64
#define PS 16
#define NCLS 1000
#define TKW 112               // waves per image in phase 1
#define TK_CHUNK (NPIX / TKW)        // 448
#define TK_ITERS (TK_CHUNK / 64)     // 7
#define FC1_KS 16             // fc1 K-split

// ---------------------------------------------------------------------------
// K1: Harris response, masked. One 16x16 output tile per block, 20x20 g-halo.
// ---------------------------------------------------------------------------
__global__ __launch_bounds__(256) void k_harris(const float* __restrict__ x,
                                                float* __restrict__ R) {
    const int bx = blockIdx.x, by = blockIdx.y, b = blockIdx.z;
    __shared__ float G[20][21];
    __shared__ float DX[18][19];
    __shared__ float DY[18][19];
    const int tid = threadIdx.x;
    const float* xb = x + (size_t)b * 3 * NPIX;

    for (int l = tid; l < 400; l += 256) {
        int p = l / 20, q = l % 20;
        int gy = by * 16 + p - 2, gx = bx * 16 + q - 2;
        float v = 0.f;
        if (gy >= 0 && gy < HW && gx >= 0 && gx < HW) {
            int o = gy * HW + gx;
            v = (xb[o] + xb[NPIX + o] + xb[2 * NPIX + o]) / 3.0f;
        }
        G[p][q] = v;
    }
    __syncthreads();

    for (int l = tid; l < 324; l += 256) {
        int a = l / 18, c = l % 18;
        int gy = by * 16 + a - 1, gx = bx * 16 + c - 1;
        float dxv = 0.f, dyv = 0.f;
        if (gy >= 0 && gy < HW && gx >= 0 && gx < HW) {
            dxv = (G[a][c + 2] - G[a][c]) + (G[a + 1][c + 2] - G[a + 1][c]) +
                  (G[a + 2][c + 2] - G[a + 2][c]);
            dyv = (G[a + 2][c] + G[a + 2][c + 1] + G[a + 2][c + 2]) -
                  (G[a][c] + G[a][c + 1] + G[a][c + 2]);
        }
        DX[a][c] = dxv;
        DY[a][c] = dyv;
    }
    __syncthreads();

    const int ty = tid / 16, tx = tid % 16;
    const int gy = by * 16 + ty, gx = bx * 16 + tx;
    float outv = 0.f;
    if (gy >= PS && gy < HW - PS && gx >= PS && gx < HW - PS) {
        const float gw[3][3] = {{1.f/16.f, 2.f/16.f, 1.f/16.f},
                                {2.f/16.f, 4.f/16.f, 2.f/16.f},
                                {1.f/16.f, 2.f/16.f, 1.f/16.f}};
        float sxx = 0.f, syy = 0.f, sxy = 0.f;
        #pragma unroll
        for (int u = 0; u < 3; u++)
            #pragma unroll
            for (int v = 0; v < 3; v++) {
                float dv = DX[ty + u][tx + v];
                float ev = DY[ty + u][tx + v];
                float w = gw[u][v];
                sxx += w * dv * dv;
                syy += w * ev * ev;
                sxy += w * dv * ev;
            }
        float tr = sxx + syy;
        outv = sxx * syy - sxy * sxy - 0.04f * tr * tr;
    }
    R[(size_t)b * NPIX + gy * HW + gx] = outv;
}

// ---------------------------------------------------------------------------
// Top-64: in-wave bitonic selection on packed 64-bit keys.
// key = monotone(value) << 32 | ~index  -> order == (value desc, index asc).
// ---------------------------------------------------------------------------
__device__ __forceinline__ uint64_t tk_pack(float v, int idx) {
    uint32_t u = __float_as_uint(v);
    u = (u & 0x80000000u) ? ~u : (u | 0x80000000u);
    return ((uint64_t)u << 32) | (uint32_t)(~idx);
}

__device__ __forceinline__ uint64_t tk_sort_asc(uint64_t k, int lane) {
    #pragma unroll
    for (int size = 2; size <= 64; size <<= 1) {
        #pragma unroll
        for (int stride = size >> 1; stride >= 1; stride >>= 1) {
            uint64_t o = __shfl_xor(k, stride, 64);
            bool up = ((lane & size) == 0);
            bool keepmax = (((lane & stride) != 0) == up);
            k = keepmax ? (k > o ? k : o) : (k < o ? k : o);
        }
    }
    return k;
}

__device__ __forceinline__ uint64_t tk_clean_desc(uint64_t k, int lane) {
    #pragma unroll
    for (int stride = 32; stride >= 1; stride >>= 1) {
        uint64_t o = __shfl_xor(k, stride, 64);
        bool keepmax = ((lane & stride) == 0);
        k = keepmax ? (k > o ? k : o) : (k < o ? k : o);
    }
    return k;
}

// Phase 1: 112 waves/image, 7 batches each. grid (28, 32) x 256.
__global__ __launch_bounds__(256) void k_topk_part(const float* __restrict__ R,
                                                   uint64_t* __restrict__ cand) {
    const int img = blockIdx.y;
    const int wave = blockIdx.x * 4 + (threadIdx.x >> 6);
    const int lane = threadIdx.x & 63;
    const float* base = R + (size_t)img * NPIX + wave * TK_CHUNK;
    const int idx_base = wave * TK_CHUNK + lane;

    uint64_t T = 0;
    #pragma unroll 1
    for (int it = 0; it < TK_ITERS; it++) {
        float v = base[it * 64 + lane];
        uint64_t ck = tk_pack(v, idx_base + it * 64);
        uint64_t thr = __shfl(T, 63, 64);
        if (__ballot(ck > thr)) {
            uint64_t s = tk_sort_asc(ck, lane);
            uint64_t m = (T > s) ? T : s;
            T = tk_clean_desc(m, lane);
        }
    }
    cand[((size_t)img * TKW + wave) * 64 + lane] = T;
}

// Phase 2: one 1024-thread block per image; wave w merges runs [7w,7w+7),
// then wave 0 merges the 16 partial runs from LDS.
__global__ __launch_bounds__(1024) void k_topk_merge(const uint64_t* __restrict__ cand,
                                                     int* __restrict__ kp) {
    const int img = blockIdx.x;
    const int w = threadIdx.x >> 6, lane = threadIdx.x & 63;
    const uint64_t* cb = cand + (size_t)img * TKW * 64;
    __shared__ uint64_t S[16 * 64];

    uint64_t T = cb[(w * 7) * 64 + lane];
    #pragma unroll
    for (int r = 1; r < 7; r++) {
        uint64_t C = cb[(w * 7 + r) * 64 + (63 - lane)];
        uint64_t m = (T > C) ? T : C;
        T = tk_clean_desc(m, lane);
    }
    S[w * 64 + lane] = T;
    __syncthreads();
    if (w == 0) {
        uint64_t T2 = S[lane];
        #pragma unroll
        for (int r = 1; r < 16; r++) {
            uint64_t C = S[r * 64 + (63 - lane)];
            uint64_t m = (T2 > C) ? T2 : C;
            T2 = tk_clean_desc(m, lane);
        }
        kp[img * KP + lane] = (int)(~(uint32_t)T2);
    }
}

// ---------------------------------------------------------------------------
// K3: bilinear patch extraction (faithful swapped broadcast) + conv + relu.
// ---------------------------------------------------------------------------
__device__ __forceinline__ float gat4(const float* img, float xf, float yf) {
    bool valid = (xf >= 0.f) && (xf < 224.f) && (yf >= 0.f) && (yf < 224.f);
    if (!valid) return 0.f;
    int xi = (int)fminf(fmaxf(xf, 0.f), 223.f);
    int yi = (int)fminf(fmaxf(yf, 0.f), 223.f);
    return img[yi * HW + xi];
}

__global__ __launch_bounds__(256) void k_patch_conv(
    const float* __restrict__ x, const int* __restrict__ kp,
    const float* __restrict__ conv_w, const float* __restrict__ conv_b,
    float* __restrict__ h) {
    const int s = blockIdx.x;   // keypoint slot
    const int b = blockIdx.y;   // image
    const int tid = threadIdx.x;

    __shared__ float P[3][16][16];
    __shared__ float CW[216];
    __shared__ float CB[8];
    for (int l = tid; l < 216; l += 256) CW[l] = conv_w[l];
    if (tid < 8) CB[tid] = conv_b[tid];

    const int idx = kp[b * KP + s];
    const int row = idx / HW, col = idx % HW;
    float cy = ((float)row / 224.0f - 0.5f) * 2.0f;
    float cx = ((float)col / 224.0f - 0.5f) * 2.0f;
    cy = fminf(fmaxf(cy, -1.0f), 1.0f);
    cx = fminf(fmaxf(cx, -1.0f), 1.0f);
    const float y01 = (cy + 1.0f) * 0.5f;
    const float x01 = (cx + 1.0f) * 0.5f;
    const float rr = 16.0f / 224.0f;
    const float step = (2.0f * rr) / 15.0f;
    const float* xb = x + (size_t)b * 3 * NPIX;

    for (int e = tid; e < 768; e += 256) {
        int c = e >> 8, rem = e & 255, i = rem >> 4, j = rem & 15;
        float pj = (j == 15) ? rr : (-rr + (float)j * step);
        float pi = (i == 15) ? rr : (-rr + (float)i * step);
        // faithful bug: x-coordinate uses y01 (row), y-coordinate uses x01 (col)
        float gxn = (pj + y01) * 2.0f - 1.0f;
        float gyn = (pi + x01) * 2.0f - 1.0f;
        float gx = (gxn + 1.0f) * 0.5f * 223.0f;
        float gy = (gyn + 1.0f) * 0.5f * 223.0f;
        float x0 = floorf(gx), y0 = floorf(gy);
        float x1 = x0 + 1.0f, y1 = y0 + 1.0f;
        float wx1 = gx - x0, wy1 = gy - y0;
        float wx0 = 1.0f - wx1, wy0 = 1.0f - wy1;
        const float* img = xb + (size_t)c * NPIX;
        float acc = gat4(img, x0, y0) * (wx0 * wy0)
                  + gat4(img, x1, y0) * (wx1 * wy0)
                  + gat4(img, x0, y1) * (wx0 * wy1)
                  + gat4(img, x1, y1) * (wx1 * wy1);
        P[c][i][j] = acc;
    }
    __syncthreads();

    const int i = tid >> 4, j = tid & 15;
    const size_t mbase = ((size_t)(b * KP + s)) * 2048;
    #pragma unroll
    for (int co = 0; co < 8; co++) {
        float acc = CB[co];
        #pragma unroll
        for (int ci = 0; ci < 3; ci++)
            #pragma unroll
            for (int di = 0; di < 3; di++)
                #pragma unroll
                for (int dj = 0; dj < 3; dj++) {
                    int yy = i + di - 1, xx = j + dj - 1;
                    if (yy >= 0 && yy < 16 && xx >= 0 && xx < 16)
                        acc += P[ci][yy][xx] * CW[co * 27 + ci * 9 + di * 3 + dj];
                }
        h[mbase + co * 256 + tid] = fmaxf(acc, 0.0f);
    }
}

// ---------------------------------------------------------------------------
// K4: fc1 partial GEMM. grid (32 m-tiles, 16 k-slices) x 256.
// M-tile 64, K-slice 128 (2 chunks of 64). 4x4 register tile per thread.
// LDS tiles stored k-major (A[k][m], W[k][o], pad 68) -> inner ds_read_b128
// is <=2-way conflict (free). partial[ks][m][o] scratch, no atomics.
// ---------------------------------------------------------------------------
__global__ __launch_bounds__(256) void k_fc1(
    const float* __restrict__ h, const float* __restrict__ fc1_w,
    float* __restrict__ partial) {
    const int mt = blockIdx.x;          // 0..31
    const int ks = blockIdx.y;          // 0..15
    const int tid = threadIdx.x;
    const int M0 = mt * 64;
    const int og = tid >> 4, mg = tid & 15;
    __shared__ float A[64 * 68];        // [k][m]
    __shared__ float W[64 * 68];        // [k][o]
    float acc[4][4];
    #pragma unroll
    for (int i = 0; i < 4; i++)
        #pragma unroll
        for (int j = 0; j < 4; j++) acc[i][j] = 0.f;

    #pragma unroll 1
    for (int ch = 0; ch < 2; ch++) {
        const int k0 = ks * 128 + ch * 64;
        __syncthreads();
        #pragma unroll
        for (int p = 0; p < 4; p++) {
            int row = p * 16 + (tid >> 4);      // 0..63
            int c0 = (tid & 15) * 4;            // k offset 0..60
            float4 av = *(const float4*)&h[(size_t)(M0 + row) * 2048 + k0 + c0];
            A[(c0 + 0) * 68 + row] = av.x;
            A[(c0 + 1) * 68 + row] = av.y;
            A[(c0 + 2) * 68 + row] = av.z;
            A[(c0 + 3) * 68 + row] = av.w;
            float4 wv = *(const float4*)&fc1_w[(size_t)row * 2048 + k0 + c0];
            W[(c0 + 0) * 68 + row] = wv.x;
            W[(c0 + 1) * 68 + row] = wv.y;
            W[(c0 + 2) * 68 + row] = wv.z;
            W[(c0 + 3) * 68 + row] = wv.w;
        }
        __syncthreads();
        #pragma unroll 4
        for (int k = 0; k < 64; k++) {
            float4 a = *(float4*)&A[k * 68 + mg * 4];
            float4 w = *(float4*)&W[k * 68 + og * 4];
            acc[0][0] += a.x * w.x; acc[0][1] += a.x * w.y;
            acc[0][2] += a.x * w.z; acc[0][3] += a.x * w.w;
            acc[1][0] += a.y * w.x; acc[1][1] += a.y * w.y;
            acc[1][2] += a.y * w.z; acc[1][3] += a.y * w.w;
            acc[2][0] += a.z * w.x; acc[2][1] += a.z * w.y;
            acc[2][2] += a.z * w.z; acc[2][3] += a.z * w.w;
            acc[3][0] += a.w * w.x; acc[3][1] += a.w * w.y;
            acc[3][2] += a.w * w.z; acc[3][3] += a.w * w.w;
        }
    }
    float* pb = partial + ((size_t)ks * 2048 + M0) * 64;
    #pragma unroll
    for (int mi = 0; mi < 4; mi++) {
        float4 v = make_float4(acc[mi][0], acc[mi][1], acc[mi][2], acc[mi][3]);
        *(float4*)&pb[(mg * 4 + mi) * 64 + og * 4] = v;
    }
}

// Sum 16 partials + bias + relu -> featT[(s*64+o)*32 + b], m = b*64+s.
__global__ __launch_bounds__(256) void k_fc1_post(
    const float* __restrict__ partial, const float* __restrict__ fc1_b,
    float* __restrict__ featT) {
    const int id = blockIdx.x * 256 + threadIdx.x;   // 0..131071
    const int o = id & 63, m = id >> 6;
    float s = 0.f;
    #pragma unroll
    for (int ks = 0; ks < FC1_KS; ks++) s += partial[(size_t)ks * 131072 + id];
    s = fmaxf(s + fc1_b[o], 0.f);
    featT[(size_t)((m & 63) * 64 + o) * 32 + (m >> 6)] = s;
}

// ---------------------------------------------------------------------------
// K5a: init out[b][c] = fc2_b[c]
// ---------------------------------------------------------------------------
__global__ __launch_bounds__(256) void k_bias(const float* __restrict__ fc2_b,
                                              float* __restrict__ out) {
    int id = blockIdx.x * 256 + threadIdx.x;
    if (id < BATCH * NCLS) out[id] = fc2_b[id % NCLS];
}

// ---------------------------------------------------------------------------
// K5b: fc2 out[b][c] += sum_k featT[k][b]*fc2_w[c][k], K split 8 ways.
// ---------------------------------------------------------------------------
__global__ __launch_bounds__(256) void k_fc2(
    const float* __restrict__ featT, const float* __restrict__ fc2_w,
    float* __restrict__ out) {
    const int c0 = blockIdx.x * 8;
    const int kbase = blockIdx.y * 512;
    const int tid = threadIdx.x;
    const int b = tid & 31, kg = tid >> 5;
    __shared__ float F[128 * 36];
    __shared__ float Wc[8 * 128];
    __shared__ float Red[8 * 8 * 32];

    float acc[8];
    #pragma unroll
    for (int cl = 0; cl < 8; cl++) acc[cl] = 0.f;

    #pragma unroll 1
    for (int ch = 0; ch < 4; ch++) {
        const int k0 = kbase + ch * 128;
        __syncthreads();
        #pragma unroll
        for (int r = 0; r < 4; r++) {
            int l = tid + r * 256;
            int f = l >> 3, b4 = (l & 7) << 2;
            *(float4*)&F[f * 36 + b4] =
                *(const float4*)&featT[(size_t)(k0 + f) * 32 + b4];
        }
        {
            int cl = tid >> 5, koff = (tid & 31) << 2;
            *(float4*)&Wc[cl * 128 + koff] =
                *(const float4*)&fc2_w[(size_t)(c0 + cl) * 4096 + k0 + koff];
        }
        __syncthreads();
        #pragma unroll
        for (int cl = 0; cl < 8; cl++) {
            #pragma unroll
            for (int i = 0; i < 16; i += 4) {
                float4 wv = *(float4*)&Wc[cl * 128 + kg * 16 + i];
                int f = kg * 16 + i;
                acc[cl] += wv.x * F[f * 36 + b] + wv.y * F[(f + 1) * 36 + b] +
                           wv.z * F[(f + 2) * 36 + b] + wv.w * F[(f + 3) * 36 + b];
            }
        }
    }
    __syncthreads();
    #pragma unroll
    for (int cl = 0; cl < 8; cl++) Red[(kg * 8 + cl) * 32 + b] = acc[cl];
    __syncthreads();
    const int cl2 = tid >> 5, b2 = tid & 31;
    float s = 0.f;
    #pragma unroll
    for (int g = 0; g < 8; g++) s += Red[(g * 8 + cl2) * 32 + b2];
    atomicAdd(&out[b2 * NCLS + c0 + cl2], s);
}

// ---------------------------------------------------------------------------
extern "C" void kernel_launch(void* const* d_in, const int* in_sizes, int n_in,
                              void* d_out, int out_size, void* d_ws, size_t ws_size,
                              hipStream_t stream) {
    const float* x      = (const float*)d_in[0];
    const float* conv_w = (const float*)d_in[1];
    const float* conv_b = (const float*)d_in[2];
    const float* fc1_w  = (const float*)d_in[3];
    const float* fc1_b  = (const float*)d_in[4];
    const float* fc2_w  = (const float*)d_in[5];
    const float* fc2_b  = (const float*)d_in[6];
    float* out = (float*)d_out;

    // ws layout. Region0 (8.39 MB) holds R (6.42 MB) + cand (1.84 MB) early,
    // then is reused as fc1 partial[16][2048][64] (8.39 MB) — R/cand are dead
    // before k_fc1 runs (stream-ordered).
    char* base = (char*)d_ws;
    const size_t region0 = (size_t)FC1_KS * 2048 * 64 * 4;       // 8.39 MB
    float*    R       = (float*)base;                            // 6.42 MB
    uint64_t* cand    = (uint64_t*)(base + (size_t)BATCH * NPIX * 4);  // 1.84 MB
    float*    partial = (float*)base;                            // alias
    float*    h       = (float*)(base + region0);                // 16.78 MB
    float*    featT   = h + (size_t)2048 * 2048;                 // 0.52 MB
    int*      kp      = (int*)(featT + (size_t)4096 * 32);       // 8 KB

    k_harris<<<dim3(14, 14, 32), 256, 0, stream>>>(x, R);
    k_topk_part<<<dim3(28, 32), 256, 0, stream>>>(R, cand);
    k_topk_merge<<<32, 1024, 0, stream>>>(cand, kp);
    k_patch_conv<<<dim3(KP, BATCH), 256, 0, stream>>>(x, kp, conv_w, conv_b, h);
    k_fc1<<<dim3(32, FC1_KS), 256, 0, stream>>>(h, fc1_w, partial);
    k_fc1_post<<<512, 256, 0, stream>>>(partial, fc1_b, featT);
    k_bias<<<(BATCH * NCLS + 255) / 256, 256, 0, stream>>>(fc2_b, out);
    k_fc2<<<dim3(125, 8), 256, 0, stream>>>(featT, fc2_w, out);
}

// Round 5
// 186.045 us; speedup vs baseline: 3.2486x; 1.0027x over previous
//
#include <hip/hip_runtime.h>
#include <cstdint>
#include <math.h>

#define HW 224
#define NPIX (HW*HW)          // 50176 = 784*64
#define BATCH 32
#define KP 64
#define PS 16
#define NCLS 1000
#define TKW 112               // 64-candidate runs per image (28 bands x 4 waves)
#define FC1_KS 16             // fc1 K-split

// ---------------------------------------------------------------------------
// Top-64 helpers: in-wave bitonic selection on packed 64-bit keys.
// key = monotone(value) << 32 | ~index  -> order == (value desc, index asc).
// ---------------------------------------------------------------------------
__device__ __forceinline__ uint64_t tk_pack(float v, int idx) {
    uint32_t u = __float_as_uint(v);
    u = (u & 0x80000000u) ? ~u : (u | 0x80000000u);
    return ((uint64_t)u << 32) | (uint32_t)(~idx);
}

__device__ __forceinline__ uint64_t tk_sort_asc(uint64_t k, int lane) {
    #pragma unroll
    for (int size = 2; size <= 64; size <<= 1) {
        #pragma unroll
        for (int stride = size >> 1; stride >= 1; stride >>= 1) {
            uint64_t o = __shfl_xor(k, stride, 64);
            bool up = ((lane & size) == 0);
            bool keepmax = (((lane & stride) != 0) == up);
            k = keepmax ? (k > o ? k : o) : (k < o ? k : o);
        }
    }
    return k;
}

__device__ __forceinline__ uint64_t tk_clean_desc(uint64_t k, int lane) {
    #pragma unroll
    for (int stride = 32; stride >= 1; stride >>= 1) {
        uint64_t o = __shfl_xor(k, stride, 64);
        bool keepmax = ((lane & stride) == 0);
        k = keepmax ? (k > o ? k : o) : (k < o ? k : o);
    }
    return k;
}

// ---------------------------------------------------------------------------
// K1: FUSED Harris + per-band top-64. One block per (8-row band, image).
// Grayscale halo rows row0-2..row0+9 in LDS (col-shifted by 1 with zero pads);
// dx/dy rows row0-1..row0+8; R for the band's 1792 px; then each of the 4
// waves runs bitonic top-64 over its contiguous 448-px chunk.
// Masked-out pixels contribute exact 0.0 (same as reference's R*mask).
// ---------------------------------------------------------------------------
__global__ __launch_bounds__(256) void k_harris_topk(const float* __restrict__ x,
                                                     uint64_t* __restrict__ cand) {
    const int r = blockIdx.x, b = blockIdx.y;
    const int tid = threadIdx.x;
    const int row0 = r * 8;
    __shared__ float G[12][228];
    __shared__ float DXs[10][228];
    __shared__ float DYs[10][228];
    __shared__ float RB[1792];
    const float* xb = x + (size_t)b * 3 * NPIX;

    // grayscale stage (stored at col+1; cols 0 and 225 are zero pads)
    for (int l = tid; l < 12 * 224; l += 256) {
        int gr = l / 224, gc = l % 224;
        int gy = row0 - 2 + gr;
        float v = 0.f;
        if (gy >= 0 && gy < HW) {
            int o = gy * HW + gc;
            v = (xb[o] + xb[NPIX + o] + xb[2 * NPIX + o]) / 3.0f;
        }
        G[gr][gc + 1] = v;
    }
    if (tid < 12) { G[tid][0] = 0.f; G[tid][225] = 0.f; }
    if (tid < 10) { DXs[tid][0] = 0.f; DXs[tid][225] = 0.f;
                    DYs[tid][0] = 0.f; DYs[tid][225] = 0.f; }
    __syncthreads();

    // Sobel dx/dy (zero outside image: gauss of dx^2 sees dx==0 beyond edges)
    for (int l = tid; l < 10 * 224; l += 256) {
        int dr = l / 224, dc = l % 224;
        int ay = row0 - 1 + dr;
        float dxv = 0.f, dyv = 0.f;
        if (ay >= 0 && ay < HW) {
            dxv = (G[dr][dc + 2] - G[dr][dc]) + (G[dr + 1][dc + 2] - G[dr + 1][dc]) +
                  (G[dr + 2][dc + 2] - G[dr + 2][dc]);
            dyv = (G[dr + 2][dc] + G[dr + 2][dc + 1] + G[dr + 2][dc + 2]) -
                  (G[dr][dc] + G[dr][dc + 1] + G[dr][dc + 2]);
        }
        DXs[dr][dc + 1] = dxv;
        DYs[dr][dc + 1] = dyv;
    }
    __syncthreads();

    // Harris response for band rows row0..row0+7 (masked -> exact 0)
    for (int l = tid; l < 1792; l += 256) {
        int rr = l / 224, c = l % 224;
        int gy = row0 + rr;
        float outv = 0.f;
        if (gy >= PS && gy < HW - PS && c >= PS && c < HW - PS) {
            const float gw[3][3] = {{1.f/16.f, 2.f/16.f, 1.f/16.f},
                                    {2.f/16.f, 4.f/16.f, 2.f/16.f},
                                    {1.f/16.f, 2.f/16.f, 1.f/16.f}};
            float sxx = 0.f, syy = 0.f, sxy = 0.f;
            #pragma unroll
            for (int u = 0; u < 3; u++)
                #pragma unroll
                for (int v = 0; v < 3; v++) {
                    float dv = DXs[rr + u][c + v];
                    float ev = DYs[rr + u][c + v];
                    float w = gw[u][v];
                    sxx += w * dv * dv;
                    syy += w * ev * ev;
                    sxy += w * dv * ev;
                }
            float tr = sxx + syy;
            outv = sxx * syy - sxy * sxy - 0.04f * tr * tr;
        }
        RB[l] = outv;
    }
    __syncthreads();

    // per-wave top-64 over contiguous 448-px chunk
    const int w = tid >> 6, lane = tid & 63;
    const int chunk = w * 448;
    const int gbase = row0 * 224 + chunk;
    uint64_t T = 0;
    #pragma unroll 1
    for (int it = 0; it < 7; it++) {
        float v = RB[chunk + it * 64 + lane];
        uint64_t ck = tk_pack(v, gbase + it * 64 + lane);
        uint64_t thr = __shfl(T, 63, 64);
        if (__ballot(ck > thr)) {
            uint64_t s = tk_sort_asc(ck, lane);
            uint64_t m = (T > s) ? T : s;
            T = tk_clean_desc(m, lane);
        }
    }
    cand[((size_t)b * TKW + r * 4 + w) * 64 + lane] = T;
}

// ---------------------------------------------------------------------------
// K2: merge 112 sorted runs per image. Wave w merges runs [7w,7w+7), then
// wave 0 merges the 16 partials from LDS.
// ---------------------------------------------------------------------------
__global__ __launch_bounds__(1024) void k_topk_merge(const uint64_t* __restrict__ cand,
                                                     int* __restrict__ kp) {
    const int img = blockIdx.x;
    const int w = threadIdx.x >> 6, lane = threadIdx.x & 63;
    const uint64_t* cb = cand + (size_t)img * TKW * 64;
    __shared__ uint64_t S[16 * 64];

    uint64_t T = cb[(w * 7) * 64 + lane];
    #pragma unroll
    for (int r = 1; r < 7; r++) {
        uint64_t C = cb[(w * 7 + r) * 64 + (63 - lane)];
        uint64_t m = (T > C) ? T : C;
        T = tk_clean_desc(m, lane);
    }
    S[w * 64 + lane] = T;
    __syncthreads();
    if (w == 0) {
        uint64_t T2 = S[lane];
        #pragma unroll
        for (int r = 1; r < 16; r++) {
            uint64_t C = S[r * 64 + (63 - lane)];
            uint64_t m = (T2 > C) ? T2 : C;
            T2 = tk_clean_desc(m, lane);
        }
        kp[img * KP + lane] = (int)(~(uint32_t)T2);
    }
}

// ---------------------------------------------------------------------------
// K3: bilinear patch extraction (faithful swapped broadcast) + conv + relu.
// ---------------------------------------------------------------------------
__device__ __forceinline__ float gat4(const float* img, float xf, float yf) {
    bool valid = (xf >= 0.f) && (xf < 224.f) && (yf >= 0.f) && (yf < 224.f);
    if (!valid) return 0.f;
    int xi = (int)fminf(fmaxf(xf, 0.f), 223.f);
    int yi = (int)fminf(fmaxf(yf, 0.f), 223.f);
    return img[yi * HW + xi];
}

__global__ __launch_bounds__(256) void k_patch_conv(
    const float* __restrict__ x, const int* __restrict__ kp,
    const float* __restrict__ conv_w, const float* __restrict__ conv_b,
    float* __restrict__ h) {
    const int s = blockIdx.x;   // keypoint slot
    const int b = blockIdx.y;   // image
    const int tid = threadIdx.x;

    __shared__ float P[3][16][16];
    __shared__ float CW[216];
    __shared__ float CB[8];
    for (int l = tid; l < 216; l += 256) CW[l] = conv_w[l];
    if (tid < 8) CB[tid] = conv_b[tid];

    const int idx = kp[b * KP + s];
    const int row = idx / HW, col = idx % HW;
    float cy = ((float)row / 224.0f - 0.5f) * 2.0f;
    float cx = ((float)col / 224.0f - 0.5f) * 2.0f;
    cy = fminf(fmaxf(cy, -1.0f), 1.0f);
    cx = fminf(fmaxf(cx, -1.0f), 1.0f);
    const float y01 = (cy + 1.0f) * 0.5f;
    const float x01 = (cx + 1.0f) * 0.5f;
    const float rr = 16.0f / 224.0f;
    const float step = (2.0f * rr) / 15.0f;
    const float* xb = x + (size_t)b * 3 * NPIX;

    for (int e = tid; e < 768; e += 256) {
        int c = e >> 8, rem = e & 255, i = rem >> 4, j = rem & 15;
        float pj = (j == 15) ? rr : (-rr + (float)j * step);
        float pi = (i == 15) ? rr : (-rr + (float)i * step);
        // faithful bug: x-coordinate uses y01 (row), y-coordinate uses x01 (col)
        float gxn = (pj + y01) * 2.0f - 1.0f;
        float gyn = (pi + x01) * 2.0f - 1.0f;
        float gx = (gxn + 1.0f) * 0.5f * 223.0f;
        float gy = (gyn + 1.0f) * 0.5f * 223.0f;
        float x0 = floorf(gx), y0 = floorf(gy);
        float x1 = x0 + 1.0f, y1 = y0 + 1.0f;
        float wx1 = gx - x0, wy1 = gy - y0;
        float wx0 = 1.0f - wx1, wy0 = 1.0f - wy1;
        const float* img = xb + (size_t)c * NPIX;
        float acc = gat4(img, x0, y0) * (wx0 * wy0)
                  + gat4(img, x1, y0) * (wx1 * wy0)
                  + gat4(img, x0, y1) * (wx0 * wy1)
                  + gat4(img, x1, y1) * (wx1 * wy1);
        P[c][i][j] = acc;
    }
    __syncthreads();

    const int i = tid >> 4, j = tid & 15;
    const size_t mbase = ((size_t)(b * KP + s)) * 2048;
    #pragma unroll
    for (int co = 0; co < 8; co++) {
        float acc = CB[co];
        #pragma unroll
        for (int ci = 0; ci < 3; ci++)
            #pragma unroll
            for (int di = 0; di < 3; di++)
                #pragma unroll
                for (int dj = 0; dj < 3; dj++) {
                    int yy = i + di - 1, xx = j + dj - 1;
                    if (yy >= 0 && yy < 16 && xx >= 0 && xx < 16)
                        acc += P[ci][yy][xx] * CW[co * 27 + ci * 9 + di * 3 + dj];
                }
        h[mbase + co * 256 + tid] = fmaxf(acc, 0.0f);
    }
}

// ---------------------------------------------------------------------------
// K4: fc1 partial GEMM. grid (32 m-tiles, 16 k-slices) x 256.
// ---------------------------------------------------------------------------
__global__ __launch_bounds__(256) void k_fc1(
    const float* __restrict__ h, const float* __restrict__ fc1_w,
    float* __restrict__ partial) {
    const int mt = blockIdx.x;          // 0..31
    const int ks = blockIdx.y;          // 0..15
    const int tid = threadIdx.x;
    const int M0 = mt * 64;
    const int og = tid >> 4, mg = tid & 15;
    __shared__ float A[64 * 68];        // [k][m]
    __shared__ float W[64 * 68];        // [k][o]
    float acc[4][4];
    #pragma unroll
    for (int i = 0; i < 4; i++)
        #pragma unroll
        for (int j = 0; j < 4; j++) acc[i][j] = 0.f;

    #pragma unroll 1
    for (int ch = 0; ch < 2; ch++) {
        const int k0 = ks * 128 + ch * 64;
        __syncthreads();
        #pragma unroll
        for (int p = 0; p < 4; p++) {
            int row = p * 16 + (tid >> 4);      // 0..63
            int c0 = (tid & 15) * 4;            // k offset 0..60
            float4 av = *(const float4*)&h[(size_t)(M0 + row) * 2048 + k0 + c0];
            A[(c0 + 0) * 68 + row] = av.x;
            A[(c0 + 1) * 68 + row] = av.y;
            A[(c0 + 2) * 68 + row] = av.z;
            A[(c0 + 3) * 68 + row] = av.w;
            float4 wv = *(const float4*)&fc1_w[(size_t)row * 2048 + k0 + c0];
            W[(c0 + 0) * 68 + row] = wv.x;
            W[(c0 + 1) * 68 + row] = wv.y;
            W[(c0 + 2) * 68 + row] = wv.z;
            W[(c0 + 3) * 68 + row] = wv.w;
        }
        __syncthreads();
        #pragma unroll 4
        for (int k = 0; k < 64; k++) {
            float4 a = *(float4*)&A[k * 68 + mg * 4];
            float4 w = *(float4*)&W[k * 68 + og * 4];
            acc[0][0] += a.x * w.x; acc[0][1] += a.x * w.y;
            acc[0][2] += a.x * w.z; acc[0][3] += a.x * w.w;
            acc[1][0] += a.y * w.x; acc[1][1] += a.y * w.y;
            acc[1][2] += a.y * w.z; acc[1][3] += a.y * w.w;
            acc[2][0] += a.z * w.x; acc[2][1] += a.z * w.y;
            acc[2][2] += a.z * w.z; acc[2][3] += a.z * w.w;
            acc[3][0] += a.w * w.x; acc[3][1] += a.w * w.y;
            acc[3][2] += a.w * w.z; acc[3][3] += a.w * w.w;
        }
    }
    float* pb = partial + ((size_t)ks * 2048 + M0) * 64;
    #pragma unroll
    for (int mi = 0; mi < 4; mi++) {
        float4 v = make_float4(acc[mi][0], acc[mi][1], acc[mi][2], acc[mi][3]);
        *(float4*)&pb[(mg * 4 + mi) * 64 + og * 4] = v;
    }
}

// Sum 16 partials + bias + relu -> featT; also seed out[b][c] = fc2_b[c]
// (d_out is poisoned before every launch; fc2 atomically accumulates later).
__global__ __launch_bounds__(256) void k_fc1_post(
    const float* __restrict__ partial, const float* __restrict__ fc1_b,
    const float* __restrict__ fc2_b, float* __restrict__ featT,
    float* __restrict__ out) {
    const int id = blockIdx.x * 256 + threadIdx.x;   // 0..131071
    const int o = id & 63, m = id >> 6;
    float s = 0.f;
    #pragma unroll
    for (int ks = 0; ks < FC1_KS; ks++) s += partial[(size_t)ks * 131072 + id];
    s = fmaxf(s + fc1_b[o], 0.f);
    featT[(size_t)((m & 63) * 64 + o) * 32 + (m >> 6)] = s;
    if (id < BATCH * NCLS) out[id] = fc2_b[id % NCLS];
}

// ---------------------------------------------------------------------------
// K5: fc2 out[b][c] += sum_k featT[k][b]*fc2_w[c][k], K split 16 ways.
// grid (125, 16): 8 classes x K-slice of 256 (2 chunks of 128).
// ---------------------------------------------------------------------------
__global__ __launch_bounds__(256) void k_fc2(
    const float* __restrict__ featT, const float* __restrict__ fc2_w,
    float* __restrict__ out) {
    const int c0 = blockIdx.x * 8;
    const int kbase = blockIdx.y * 256;
    const int tid = threadIdx.x;
    const int b = tid & 31, kg = tid >> 5;
    __shared__ float F[128 * 36];
    __shared__ float Wc[8 * 128];
    __shared__ float Red[8 * 8 * 32];

    float acc[8];
    #pragma unroll
    for (int cl = 0; cl < 8; cl++) acc[cl] = 0.f;

    #pragma unroll 1
    for (int ch = 0; ch < 2; ch++) {
        const int k0 = kbase + ch * 128;
        __syncthreads();
        #pragma unroll
        for (int r = 0; r < 4; r++) {
            int l = tid + r * 256;
            int f = l >> 3, b4 = (l & 7) << 2;
            *(float4*)&F[f * 36 + b4] =
                *(const float4*)&featT[(size_t)(k0 + f) * 32 + b4];
        }
        {
            int cl = tid >> 5, koff = (tid & 31) << 2;
            *(float4*)&Wc[cl * 128 + koff] =
                *(const float4*)&fc2_w[(size_t)(c0 + cl) * 4096 + k0 + koff];
        }
        __syncthreads();
        #pragma unroll
        for (int cl = 0; cl < 8; cl++) {
            #pragma unroll
            for (int i = 0; i < 16; i += 4) {
                float4 wv = *(float4*)&Wc[cl * 128 + kg * 16 + i];
                int f = kg * 16 + i;
                acc[cl] += wv.x * F[f * 36 + b] + wv.y * F[(f + 1) * 36 + b] +
                           wv.z * F[(f + 2) * 36 + b] + wv.w * F[(f + 3) * 36 + b];
            }
        }
    }
    __syncthreads();
    #pragma unroll
    for (int cl = 0; cl < 8; cl++) Red[(kg * 8 + cl) * 32 + b] = acc[cl];
    __syncthreads();
    const int cl2 = tid >> 5, b2 = tid & 31;
    float s = 0.f;
    #pragma unroll
    for (int g = 0; g < 8; g++) s += Red[(g * 8 + cl2) * 32 + b2];
    atomicAdd(&out[b2 * NCLS + c0 + cl2], s);
}

// ---------------------------------------------------------------------------
extern "C" void kernel_launch(void* const* d_in, const int* in_sizes, int n_in,
                              void* d_out, int out_size, void* d_ws, size_t ws_size,
                              hipStream_t stream) {
    const float* x      = (const float*)d_in[0];
    const float* conv_w = (const float*)d_in[1];
    const float* conv_b = (const float*)d_in[2];
    const float* fc1_w  = (const float*)d_in[3];
    const float* fc1_b  = (const float*)d_in[4];
    const float* fc2_w  = (const float*)d_in[5];
    const float* fc2_b  = (const float*)d_in[6];
    float* out = (float*)d_out;

    // ws layout. Region0 (8.39 MB): cand (1.84 MB) early, then reused as
    // fc1 partial[16][2048][64] — cand is dead before k_fc1 (stream-ordered).
    char* base = (char*)d_ws;
    const size_t region0 = (size_t)FC1_KS * 2048 * 64 * 4;       // 8.39 MB
    uint64_t* cand    = (uint64_t*)base;                         // 1.84 MB
    float*    partial = (float*)base;                            // alias
    float*    h       = (float*)(base + region0);                // 16.78 MB
    float*    featT   = h + (size_t)2048 * 2048;                 // 0.52 MB
    int*      kp      = (int*)(featT + (size_t)4096 * 32);       // 8 KB

    k_harris_topk<<<dim3(28, 32), 256, 0, stream>>>(x, cand);
    k_topk_merge<<<32, 1024, 0, stream>>>(cand, kp);
    k_patch_conv<<<dim3(KP, BATCH), 256, 0, stream>>>(x, kp, conv_w, conv_b, h);
    k_fc1<<<dim3(32, FC1_KS), 256, 0, stream>>>(h, fc1_w, partial);
    k_fc1_post<<<512, 256, 0, stream>>>(partial, fc1_b, fc2_b, featT, out);
    k_fc2<<<dim3(125, 16), 256, 0, stream>>>(featT, fc2_w, out);
}